// Round 2
// baseline (191.012 us; speedup 1.0000x reference)
//
#include <hip/hip_runtime.h>

// ---------------------------------------------------------------------------
// MultiHeadAttention: b=2, n=2048, EMB=1024, heads=16, head_dim=64
// R13: attn LDS-BW fix. R12 counters showed 288 ds_read_b128/CU/tile
//  ~= the whole tile budget (LDS-read-bound; DMA pipeline was neutral).
//  attn now: 4 waves x 32 q-rows each (2 q-groups). kf/vf fragments read
//  ONCE per tile and reused for both q-groups -> 160 b128 reads/CU/tile
//  (-44%). Ring buffer (depth 3) + counted vmcnt(4) + single barrier kept.
//  - gemm_qkv: (256,3), 128x128 tile -- unchanged (best measured).
//  - gemm_out: 128x64 tile, 256 thr, grid (16,32) -- unchanged.
// ---------------------------------------------------------------------------

typedef short short8  __attribute__((ext_vector_type(8)));
typedef float floatx4 __attribute__((ext_vector_type(4)));

#define SEQ   2048
#define BATCH 2
#define NH    16
#define HD    64
#define EMB   1024

// softmax_e(E/32) == softmax_2(E * log2e/32); folded into Q.
#define QSCALE 0.045084220027780106f

__device__ __forceinline__ unsigned short f32_bf16(float f) {
    unsigned int u = __float_as_uint(f);
    u += 0x7FFF + ((u >> 16) & 1);      // round-to-nearest-even
    return (unsigned short)(u >> 16);
}

// pack two floats to bf16x2 (round-to-nearest, ties-away): 2 adds + 1 perm
__device__ __forceinline__ unsigned int pk_bf16(float lo, float hi) {
    return __builtin_amdgcn_perm(__float_as_uint(hi) + 0x8000u,
                                 __float_as_uint(lo) + 0x8000u, 0x07060302u);
}

// async global->LDS, 16B per lane; LDS dest = wave-uniform base + lane*16
__device__ __forceinline__ void gl_lds16(const unsigned short* g,
                                         unsigned short* l) {
    __builtin_amdgcn_global_load_lds(
        (const __attribute__((address_space(1))) unsigned int*)g,
        (__attribute__((address_space(3))) unsigned int*)l, 16, 0, 0);
}

// ---------------------------------------------------------------------------
// fp32 -> bf16 conversion for x, Wq, Wk, Wv, Wo (laid contiguously at ws+0)
// ---------------------------------------------------------------------------
__global__ __launch_bounds__(256) void convert_all(
        const float* __restrict__ x,  const float* __restrict__ wq,
        const float* __restrict__ wk, const float* __restrict__ wv,
        const float* __restrict__ wo, unsigned short* __restrict__ dst) {
    int i = (blockIdx.x * 256 + threadIdx.x) * 4;
    const float* src; int off;
    if      (i < 4194304) { src = x;  off = 0; }
    else if (i < 5242880) { src = wq; off = 4194304; }
    else if (i < 6291456) { src = wk; off = 5242880; }
    else if (i < 7340032) { src = wv; off = 6291456; }
    else                  { src = wo; off = 7340032; }
    float4 v = *(const float4*)(src + (i - off));
    uint2 o;
    o.x = pk_bf16(v.x, v.y);
    o.y = pk_bf16(v.z, v.w);
    *(uint2*)(dst + i) = o;
}

// ---------------------------------------------------------------------------
// QKV GEMM: C[4096,1024] = A[4096,1024] * B[1024,1024]^T + bias
// 256 thr / 4 waves, 128x128 tile, global_load_lds + XOR-chunk swizzle.
// MODE 0: bf16 | MODE 1: bf16*QSCALE (Q) | MODE 2: bf16 -> VT scatter (V)
// ---------------------------------------------------------------------------
template <int MODE>
__device__ __forceinline__ void gemm_bt_core(
        unsigned short (* __restrict__ sA)[64],
        unsigned short (* __restrict__ sB)[64],
        const unsigned short* __restrict__ A,
        const unsigned short* __restrict__ B,
        const float* __restrict__ bias,
        unsigned short* __restrict__ outb) {
    const int t    = threadIdx.x;
    const int wave = t >> 6, lane = t & 63;
    const int l15  = lane & 15, quad = lane >> 4;
    const int wm   = (wave >> 1) * 64, wn = (wave & 1) * 64;
    const int m0   = blockIdx.y * 128,  n0 = blockIdx.x * 128;
    const int srow = lane >> 3;                 // 0..7
    const int sch  = ((lane & 7) ^ srow) * 8;   // swizzled source chunk

    floatx4 acc[4][4] = {};

    for (int k0 = 0; k0 < EMB; k0 += 64) {
        for (int i = 0; i < 4; ++i) {
            int rr  = wave * 32 + i * 8;        // wave-uniform row base
            int row = rr + srow;
            gl_lds16(&A[(size_t)(m0 + row) * EMB + k0 + sch], &sA[0][0] + rr * 64);
            gl_lds16(&B[(size_t)(n0 + row) * EMB + k0 + sch], &sB[0][0] + rr * 64);
        }
        __syncthreads();
        for (int ks = 0; ks < 2; ++ks) {
            const int ch = (((ks * 4) + quad) ^ (l15 & 7)) * 8;
            short8 af[4], bf[4];
            for (int i = 0; i < 4; ++i)
                af[i] = *(const short8*)&sA[wm + i * 16 + l15][ch];
            for (int j = 0; j < 4; ++j)
                bf[j] = *(const short8*)&sB[wn + j * 16 + l15][ch];
            for (int i = 0; i < 4; ++i)
                for (int j = 0; j < 4; ++j)
                    acc[i][j] = __builtin_amdgcn_mfma_f32_16x16x32_bf16(
                        af[i], bf[j], acc[i][j], 0, 0, 0);
        }
        __syncthreads();
    }
    // C/D layout: col = lane&15, row = quad*4 + reg
    if (MODE == 2) {
        // V: write transposed VT[(b*16+h)*64 + d][seq]
        for (int i = 0; i < 4; ++i) {
            int row = m0 + wm + i * 16 + quad * 4;
            int bb  = row >> 11, seq = row & 2047;
            for (int j = 0; j < 4; ++j) {
                int col = n0 + wn + j * 16 + l15;
                float bv = bias[col];
                int vtrow = (bb * 16 + (col >> 6)) * 64 + (col & 63);
                uint2 pk;
                pk.x = pk_bf16(acc[i][j][0] + bv, acc[i][j][1] + bv);
                pk.y = pk_bf16(acc[i][j][2] + bv, acc[i][j][3] + bv);
                *(uint2*)&outb[(size_t)vtrow * SEQ + seq] = pk;
            }
        }
    } else {
        const float sc2 = (MODE == 1) ? QSCALE : 1.0f;
        for (int i = 0; i < 4; ++i) {
            int row = m0 + wm + i * 16 + quad * 4;
            for (int j = 0; j < 4; ++j) {
                int col = n0 + wn + j * 16 + l15;
                float bv = bias[col];
                for (int r = 0; r < 4; ++r) {
                    float v = (acc[i][j][r] + bv) * sc2;
                    outb[(size_t)(row + r) * EMB + col] = f32_bf16(v);
                }
            }
        }
    }
}

__global__ __launch_bounds__(256, 3) void gemm_qkv(
        const unsigned short* __restrict__ xb,
        const unsigned short* __restrict__ wq,
        const unsigned short* __restrict__ wk,
        const unsigned short* __restrict__ wv,
        const float* __restrict__ bq, const float* __restrict__ bk,
        const float* __restrict__ bv,
        unsigned short* __restrict__ Q, unsigned short* __restrict__ K,
        unsigned short* __restrict__ VT) {
    __shared__ unsigned short sA[128][64];
    __shared__ unsigned short sB[128][64];
    if      (blockIdx.z == 0) gemm_bt_core<1>(sA, sB, xb, wq, bq, Q);
    else if (blockIdx.z == 1) gemm_bt_core<0>(sA, sB, xb, wk, bk, K);
    else                      gemm_bt_core<2>(sA, sB, xb, wv, bv, VT);
}

// ---------------------------------------------------------------------------
// Output GEMM (fp32 out): 128x64 tile, 256 thr / 4 waves (wave = 32m x 64n),
// grid (16,32) = 512 blocks -> 2 blocks/CU, 8 waves/CU.
// ---------------------------------------------------------------------------
__global__ __launch_bounds__(256) void gemm_out(
        const unsigned short* __restrict__ A,
        const unsigned short* __restrict__ B,
        const float* __restrict__ bias, float* __restrict__ out) {
    __shared__ unsigned short sA[128][64];
    __shared__ unsigned short sB[64][64];
    const int t    = threadIdx.x;
    const int wave = t >> 6, lane = t & 63;
    const int l15  = lane & 15, quad = lane >> 4;
    const int wm   = wave * 32;
    const int m0   = blockIdx.y * 128,  n0 = blockIdx.x * 64;
    const int srow = lane >> 3;
    const int sch  = ((lane & 7) ^ srow) * 8;

    floatx4 acc[2][4] = {};

    for (int k0 = 0; k0 < EMB; k0 += 64) {
        {
            for (int i = 0; i < 4; ++i) {     // A: wave's 32 rows
                int rr = wave * 32 + i * 8;
                gl_lds16(&A[(size_t)(m0 + rr + srow) * EMB + k0 + sch],
                         &sA[0][0] + rr * 64);
            }
            for (int i = 0; i < 2; ++i) {     // B: wave's 16 rows
                int rr = wave * 16 + i * 8;
                gl_lds16(&B[(size_t)(n0 + rr + srow) * EMB + k0 + sch],
                         &sB[0][0] + rr * 64);
            }
        }
        __syncthreads();
        for (int ks = 0; ks < 2; ++ks) {
            const int ch = (((ks * 4) + quad) ^ (l15 & 7)) * 8;
            short8 af[2], bf[4];
            for (int i = 0; i < 2; ++i)
                af[i] = *(const short8*)&sA[wm + i * 16 + l15][ch];
            for (int j = 0; j < 4; ++j)
                bf[j] = *(const short8*)&sB[j * 16 + l15][ch];
            for (int i = 0; i < 2; ++i)
                for (int j = 0; j < 4; ++j)
                    acc[i][j] = __builtin_amdgcn_mfma_f32_16x16x32_bf16(
                        af[i], bf[j], acc[i][j], 0, 0, 0);
        }
        __syncthreads();
    }
    for (int i = 0; i < 2; ++i) {
        int row = m0 + wm + i * 16 + quad * 4;
        for (int j = 0; j < 4; ++j) {
            int col = n0 + j * 16 + l15;
            float bv = bias[col];
            for (int r = 0; r < 4; ++r)
                out[(size_t)(row + r) * EMB + col] = acc[i][j][r] + bv;
        }
    }
}

// ---------------------------------------------------------------------------
// Flash attention, transposed-score, static-max softmax.
// R13: 4 waves (256 thr); each wave owns 32 q-rows = 2 q-groups of 16.
// kf/vf LDS fragments are read ONCE per tile and reused for both q-groups:
// ds_read_b128 per CU per tile 288 -> 160 (the R12 counters showed LDS-read
// BW ~= the whole tile budget). Ring buffer depth 3, one s_barrier/tile,
// counted s_waitcnt vmcnt(4) (4 DMAs/tile/wave stay in flight across the
// barrier). Safety: barrier at iter t orders all reads of slot (t-1)%3
// before iter t+1's overwrite of that slot; per-wave vmcnt(4) retires tile
// t's 4 loads before the barrier.
// Grid: x = bh (32) -> XCD locality; y = q-tile (16). 512 blocks, 2/CU,
// 8 waves/CU. LDS 66KB/block.
// ---------------------------------------------------------------------------
__global__ __launch_bounds__(256) void attn(
        const unsigned short* __restrict__ Q,
        const unsigned short* __restrict__ K,
        const unsigned short* __restrict__ VT,
        unsigned short* __restrict__ O) {
    __shared__ unsigned short sK [3][64][64];
    __shared__ unsigned short sVT[3][64][64];
    __shared__ unsigned short sP [128][72];
    const int t    = threadIdx.x;
    const int wave = t >> 6, lane = t & 63;
    const int l15  = lane & 15, quad = lane >> 4;
    const int bh   = blockIdx.x;                 // XCD-locality key
    const int b    = bh >> 4, h = bh & 15;
    const int q0   = blockIdx.y * 128;
    const size_t rowbase = (size_t)b * SEQ;
    const int colbase  = h * HD;
    const size_t vtbase = (size_t)bh * HD * SEQ;
    const int srow = lane >> 3;
    const int sch  = ((lane & 7) ^ srow) * 8;

    // Q fragments in registers (pre-scaled by log2e/32 in GEMM epilogue);
    // this wave's 32 q-rows: q0 + wave*32 + g*16 + l15
    short8 qf[2][2];   // [g][ks]
    for (int g = 0; g < 2; ++g)
        for (int ks = 0; ks < 2; ++ks)
            qf[g][ks] = *(const short8*)
                &Q[(rowbase + q0 + wave * 32 + g * 16 + l15) * EMB
                   + colbase + ks * 32 + quad * 8];

    float l_part[2] = {0.f, 0.f};
    floatx4 o_acc[2][4] = {};   // [g][mi = d-frag]; col = q (l15)

    // stage: each wave stages 16 K rows + 16 VT rows (2 gl_lds16 each)
    // prologue: tile 0 into buffer 0
    for (int i = 0; i < 2; ++i) {
        int rr  = wave * 16 + i * 8;     // wave-uniform row base
        int row = rr + srow;
        gl_lds16(&K[(rowbase + row) * EMB + colbase + sch],
                 &sK[0][0][0] + rr * 64);
        gl_lds16(&VT[vtbase + (size_t)row * SEQ + sch],
                 &sVT[0][0][0] + rr * 64);
    }

    int cur = 0;
    for (int it = 0; it < SEQ / 64; ++it) {
        if (it < SEQ / 64 - 1) {
            // stage tile it+1 into the ring slot last read at iter it-1
            int nb = cur + 1; if (nb == 3) nb = 0;
            int kt = (it + 1) * 64;
            for (int i = 0; i < 2; ++i) {
                int rr  = wave * 16 + i * 8;
                int row = rr + srow;
                gl_lds16(&K[(rowbase + kt + row) * EMB + colbase + sch],
                         &sK[nb][0][0] + rr * 64);
                gl_lds16(&VT[vtbase + (size_t)row * SEQ + kt + sch],
                         &sVT[nb][0][0] + rr * 64);
            }
            asm volatile("s_waitcnt vmcnt(4)" ::: "memory");
        } else {
            asm volatile("s_waitcnt vmcnt(0)" ::: "memory");
        }
        asm volatile("s_barrier" ::: "memory");

        const unsigned short (*cK)[64]  = sK[cur];
        const unsigned short (*cVT)[64] = sVT[cur];

        // S^T = K Q^T : s[g][mi] rows = keys mi*16+quad*4+r, col = q = l15
        floatx4 s[2][4] = {};
        for (int ks = 0; ks < 2; ++ks) {
            const int ch = (((ks * 4) + quad) ^ (l15 & 7)) * 8;
            short8 kf[4];
            for (int mi = 0; mi < 4; ++mi)
                kf[mi] = *(const short8*)&cK[mi * 16 + l15][ch];
            for (int g = 0; g < 2; ++g)
                for (int mi = 0; mi < 4; ++mi)
                    s[g][mi] = __builtin_amdgcn_mfma_f32_16x16x32_bf16(
                        kf[mi], qf[g][ks], s[g][mi], 0, 0, 0);
        }

        // p = exp2(s); per-lane l partial; pack to wave-private sP rows
        for (int g = 0; g < 2; ++g) {
            int prow = wave * 32 + g * 16 + l15;
            float lp = l_part[g];
            for (int mi = 0; mi < 4; ++mi) {
                float p0 = __builtin_amdgcn_exp2f(s[g][mi][0]);
                float p1 = __builtin_amdgcn_exp2f(s[g][mi][1]);
                float p2 = __builtin_amdgcn_exp2f(s[g][mi][2]);
                float p3 = __builtin_amdgcn_exp2f(s[g][mi][3]);
                lp += (p0 + p1) + (p2 + p3);
                uint2 pk;
                pk.x = pk_bf16(p0, p1);
                pk.y = pk_bf16(p2, p3);
                *(uint2*)&sP[prow][mi * 16 + quad * 4] = pk;
            }
            l_part[g] = lp;
        }

        // O^T += V^T P^T (sP rows wave-private; no barrier needed)
        for (int ks = 0; ks < 2; ++ks) {
            const int ch = (((ks * 4) + quad) ^ (l15 & 7)) * 8;
            short8 vf[4];
            for (int mi = 0; mi < 4; ++mi)
                vf[mi] = *(const short8*)&cVT[mi * 16 + l15][ch];
            for (int g = 0; g < 2; ++g) {
                short8 pf = *(const short8*)
                    &sP[wave * 32 + g * 16 + l15][ks * 32 + quad * 8];
                for (int mi = 0; mi < 4; ++mi)
                    o_acc[g][mi] = __builtin_amdgcn_mfma_f32_16x16x32_bf16(
                        vf[mi], pf, o_acc[g][mi], 0, 0, 0);
            }
        }
        cur = cur + 1; if (cur == 3) cur = 0;
        // NO trailing barrier: next iter's single barrier protects the ring.
    }

    // reduce l across quads (keys were spread over quad), then normalize;
    // bounce O^T through sP (wave-private rows), store coalesced
    for (int g = 0; g < 2; ++g) {
        float la = l_part[g];
        la += __shfl_xor(la, 16, 64);
        la += __shfl_xor(la, 32, 64);
        const float inv_l = 1.0f / la;
        int prow = wave * 32 + g * 16 + l15;
        for (int mi = 0; mi < 4; ++mi) {
            uint2 pk;
            pk.x = pk_bf16(o_acc[g][mi][0] * inv_l, o_acc[g][mi][1] * inv_l);
            pk.y = pk_bf16(o_acc[g][mi][2] * inv_l, o_acc[g][mi][3] * inv_l);
            *(uint2*)&sP[prow][mi * 16 + quad * 4] = pk;
        }
    }
    __builtin_amdgcn_s_waitcnt(0);  // drain lgkm before wave-private re-read
    const int ql = lane >> 2, dh = (lane & 3) * 16;
    for (int g = 0; g < 2; ++g) {
        const size_t grow = rowbase + q0 + wave * 32 + g * 16 + ql;
        for (int i = 0; i < 2; ++i) {
            uint4 v = *(const uint4*)&sP[wave * 32 + g * 16 + ql][dh + i * 8];
            *(uint4*)&O[grow * EMB + colbase + dh + i * 8] = v;
        }
    }
}

// ---------------------------------------------------------------------------
extern "C" void kernel_launch(void* const* d_in, const int* in_sizes, int n_in,
                              void* d_out, int out_size, void* d_ws, size_t ws_size,
                              hipStream_t stream) {
    const float* x  = (const float*)d_in[0];
    const float* Wq = (const float*)d_in[1];
    const float* bq = (const float*)d_in[2];
    const float* Wk = (const float*)d_in[3];
    const float* bk = (const float*)d_in[4];
    const float* Wv = (const float*)d_in[5];
    const float* bv = (const float*)d_in[6];
    const float* Wo = (const float*)d_in[7];
    const float* bo = (const float*)d_in[8];

    unsigned short* ws  = (unsigned short*)d_ws;
    unsigned short* xb  = ws;                // [4096][1024] bf16
    unsigned short* wqb = ws + 4194304;      // [1024][1024]
    unsigned short* wkb = ws + 5242880;
    unsigned short* wvb = ws + 6291456;
    unsigned short* wob = ws + 7340032;
    unsigned short* Qb  = ws + 8388608;      // [4096][1024] (pre-scaled)
    unsigned short* Kb  = ws + 12582912;     // [4096][1024]
    unsigned short* VTb = ws + 16777216;     // [32*64][2048] = V^T per (b,h)
    unsigned short* Ob  = ws + 20971520;     // attention output [4096][1024]

    convert_all<<<8192, 256, 0, stream>>>(x, Wq, Wk, Wv, Wo, ws);
    gemm_qkv<<<dim3(8, 32, 3), 256, 0, stream>>>(xb, wqb, wkb, wvb,
                                                 bq, bk, bv, Qb, Kb, VTb);
    attn<<<dim3(32, 16), 256, 0, stream>>>(Qb, Kb, VTb, Ob);
    gemm_out<<<dim3(16, 32), 256, 0, stream>>>(Ob, wob, bo, (float*)d_out);
}

// Round 3
// 179.911 us; speedup vs baseline: 1.0617x; 1.0617x over previous
//
#include <hip/hip_runtime.h>

// ---------------------------------------------------------------------------
// MultiHeadAttention: b=2, n=2048, EMB=1024, heads=16, head_dim=64
// R14: attn key-split waves. R12 was LDS-read-BW-bound (16 waves/CU x 18
//  ds_read_b128 x 12cy ~= whole tile budget); R13 cut reads but halved
//  occupancy (256thr + 66KB LDS -> 2 waves/SIMD) and regressed. R14 keeps
//  R12's block shape (512 thr, 66KB, 2 blocks/CU, 4 waves/SIMD) and splits
//  each wave's work as (qh,kh): 32 q-rows x 32 keys -> 10 b128 reads/wave
//  (was 18). Partial O/l combined once at end via f32 LDS scratch aliased
//  over the ring buffers. Ring depth 3 + counted vmcnt(2) kept.
//  - gemm_qkv / gemm_out / convert_all unchanged.
// ---------------------------------------------------------------------------

typedef short short8  __attribute__((ext_vector_type(8)));
typedef float floatx4 __attribute__((ext_vector_type(4)));

#define SEQ   2048
#define BATCH 2
#define NH    16
#define HD    64
#define EMB   1024

// softmax_e(E/32) == softmax_2(E * log2e/32); folded into Q.
#define QSCALE 0.045084220027780106f

__device__ __forceinline__ unsigned short f32_bf16(float f) {
    unsigned int u = __float_as_uint(f);
    u += 0x7FFF + ((u >> 16) & 1);      // round-to-nearest-even
    return (unsigned short)(u >> 16);
}

// pack two floats to bf16x2 (round-to-nearest, ties-away): 2 adds + 1 perm
__device__ __forceinline__ unsigned int pk_bf16(float lo, float hi) {
    return __builtin_amdgcn_perm(__float_as_uint(hi) + 0x8000u,
                                 __float_as_uint(lo) + 0x8000u, 0x07060302u);
}

// async global->LDS, 16B per lane; LDS dest = wave-uniform base + lane*16
__device__ __forceinline__ void gl_lds16(const unsigned short* g,
                                         unsigned short* l) {
    __builtin_amdgcn_global_load_lds(
        (const __attribute__((address_space(1))) unsigned int*)g,
        (__attribute__((address_space(3))) unsigned int*)l, 16, 0, 0);
}

// ---------------------------------------------------------------------------
// fp32 -> bf16 conversion for x, Wq, Wk, Wv, Wo (laid contiguously at ws+0)
// ---------------------------------------------------------------------------
__global__ __launch_bounds__(256) void convert_all(
        const float* __restrict__ x,  const float* __restrict__ wq,
        const float* __restrict__ wk, const float* __restrict__ wv,
        const float* __restrict__ wo, unsigned short* __restrict__ dst) {
    int i = (blockIdx.x * 256 + threadIdx.x) * 4;
    const float* src; int off;
    if      (i < 4194304) { src = x;  off = 0; }
    else if (i < 5242880) { src = wq; off = 4194304; }
    else if (i < 6291456) { src = wk; off = 5242880; }
    else if (i < 7340032) { src = wv; off = 6291456; }
    else                  { src = wo; off = 7340032; }
    float4 v = *(const float4*)(src + (i - off));
    uint2 o;
    o.x = pk_bf16(v.x, v.y);
    o.y = pk_bf16(v.z, v.w);
    *(uint2*)(dst + i) = o;
}

// ---------------------------------------------------------------------------
// QKV GEMM: C[4096,1024] = A[4096,1024] * B[1024,1024]^T + bias
// 256 thr / 4 waves, 128x128 tile, global_load_lds + XOR-chunk swizzle.
// MODE 0: bf16 | MODE 1: bf16*QSCALE (Q) | MODE 2: bf16 -> VT scatter (V)
// ---------------------------------------------------------------------------
template <int MODE>
__device__ __forceinline__ void gemm_bt_core(
        unsigned short (* __restrict__ sA)[64],
        unsigned short (* __restrict__ sB)[64],
        const unsigned short* __restrict__ A,
        const unsigned short* __restrict__ B,
        const float* __restrict__ bias,
        unsigned short* __restrict__ outb) {
    const int t    = threadIdx.x;
    const int wave = t >> 6, lane = t & 63;
    const int l15  = lane & 15, quad = lane >> 4;
    const int wm   = (wave >> 1) * 64, wn = (wave & 1) * 64;
    const int m0   = blockIdx.y * 128,  n0 = blockIdx.x * 128;
    const int srow = lane >> 3;                 // 0..7
    const int sch  = ((lane & 7) ^ srow) * 8;   // swizzled source chunk

    floatx4 acc[4][4] = {};

    for (int k0 = 0; k0 < EMB; k0 += 64) {
        for (int i = 0; i < 4; ++i) {
            int rr  = wave * 32 + i * 8;        // wave-uniform row base
            int row = rr + srow;
            gl_lds16(&A[(size_t)(m0 + row) * EMB + k0 + sch], &sA[0][0] + rr * 64);
            gl_lds16(&B[(size_t)(n0 + row) * EMB + k0 + sch], &sB[0][0] + rr * 64);
        }
        __syncthreads();
        for (int ks = 0; ks < 2; ++ks) {
            const int ch = (((ks * 4) + quad) ^ (l15 & 7)) * 8;
            short8 af[4], bf[4];
            for (int i = 0; i < 4; ++i)
                af[i] = *(const short8*)&sA[wm + i * 16 + l15][ch];
            for (int j = 0; j < 4; ++j)
                bf[j] = *(const short8*)&sB[wn + j * 16 + l15][ch];
            for (int i = 0; i < 4; ++i)
                for (int j = 0; j < 4; ++j)
                    acc[i][j] = __builtin_amdgcn_mfma_f32_16x16x32_bf16(
                        af[i], bf[j], acc[i][j], 0, 0, 0);
        }
        __syncthreads();
    }
    // C/D layout: col = lane&15, row = quad*4 + reg
    if (MODE == 2) {
        // V: write transposed VT[(b*16+h)*64 + d][seq]
        for (int i = 0; i < 4; ++i) {
            int row = m0 + wm + i * 16 + quad * 4;
            int bb  = row >> 11, seq = row & 2047;
            for (int j = 0; j < 4; ++j) {
                int col = n0 + wn + j * 16 + l15;
                float bv = bias[col];
                int vtrow = (bb * 16 + (col >> 6)) * 64 + (col & 63);
                uint2 pk;
                pk.x = pk_bf16(acc[i][j][0] + bv, acc[i][j][1] + bv);
                pk.y = pk_bf16(acc[i][j][2] + bv, acc[i][j][3] + bv);
                *(uint2*)&outb[(size_t)vtrow * SEQ + seq] = pk;
            }
        }
    } else {
        const float sc2 = (MODE == 1) ? QSCALE : 1.0f;
        for (int i = 0; i < 4; ++i) {
            int row = m0 + wm + i * 16 + quad * 4;
            for (int j = 0; j < 4; ++j) {
                int col = n0 + wn + j * 16 + l15;
                float bv = bias[col];
                for (int r = 0; r < 4; ++r) {
                    float v = (acc[i][j][r] + bv) * sc2;
                    outb[(size_t)(row + r) * EMB + col] = f32_bf16(v);
                }
            }
        }
    }
}

__global__ __launch_bounds__(256, 3) void gemm_qkv(
        const unsigned short* __restrict__ xb,
        const unsigned short* __restrict__ wq,
        const unsigned short* __restrict__ wk,
        const unsigned short* __restrict__ wv,
        const float* __restrict__ bq, const float* __restrict__ bk,
        const float* __restrict__ bv,
        unsigned short* __restrict__ Q, unsigned short* __restrict__ K,
        unsigned short* __restrict__ VT) {
    __shared__ unsigned short sA[128][64];
    __shared__ unsigned short sB[128][64];
    if      (blockIdx.z == 0) gemm_bt_core<1>(sA, sB, xb, wq, bq, Q);
    else if (blockIdx.z == 1) gemm_bt_core<0>(sA, sB, xb, wk, bk, K);
    else                      gemm_bt_core<2>(sA, sB, xb, wv, bv, VT);
}

// ---------------------------------------------------------------------------
// Output GEMM (fp32 out): 128x64 tile, 256 thr / 4 waves (wave = 32m x 64n),
// grid (16,32) = 512 blocks -> 2 blocks/CU, 8 waves/CU.
// ---------------------------------------------------------------------------
__global__ __launch_bounds__(256) void gemm_out(
        const unsigned short* __restrict__ A,
        const unsigned short* __restrict__ B,
        const float* __restrict__ bias, float* __restrict__ out) {
    __shared__ unsigned short sA[128][64];
    __shared__ unsigned short sB[64][64];
    const int t    = threadIdx.x;
    const int wave = t >> 6, lane = t & 63;
    const int l15  = lane & 15, quad = lane >> 4;
    const int wm   = wave * 32;
    const int m0   = blockIdx.y * 128,  n0 = blockIdx.x * 64;
    const int srow = lane >> 3;
    const int sch  = ((lane & 7) ^ srow) * 8;

    floatx4 acc[2][4] = {};

    for (int k0 = 0; k0 < EMB; k0 += 64) {
        {
            for (int i = 0; i < 4; ++i) {     // A: wave's 32 rows
                int rr = wave * 32 + i * 8;
                gl_lds16(&A[(size_t)(m0 + rr + srow) * EMB + k0 + sch],
                         &sA[0][0] + rr * 64);
            }
            for (int i = 0; i < 2; ++i) {     // B: wave's 16 rows
                int rr = wave * 16 + i * 8;
                gl_lds16(&B[(size_t)(n0 + rr + srow) * EMB + k0 + sch],
                         &sB[0][0] + rr * 64);
            }
        }
        __syncthreads();
        for (int ks = 0; ks < 2; ++ks) {
            const int ch = (((ks * 4) + quad) ^ (l15 & 7)) * 8;
            short8 af[2], bf[4];
            for (int i = 0; i < 2; ++i)
                af[i] = *(const short8*)&sA[wm + i * 16 + l15][ch];
            for (int j = 0; j < 4; ++j)
                bf[j] = *(const short8*)&sB[j * 16 + l15][ch];
            for (int i = 0; i < 2; ++i)
                for (int j = 0; j < 4; ++j)
                    acc[i][j] = __builtin_amdgcn_mfma_f32_16x16x32_bf16(
                        af[i], bf[j], acc[i][j], 0, 0, 0);
        }
        __syncthreads();
    }
    for (int i = 0; i < 2; ++i) {
        int row = m0 + wm + i * 16 + quad * 4;
        for (int j = 0; j < 4; ++j) {
            int col = n0 + j * 16 + l15;
            float bv = bias[col];
            for (int r = 0; r < 4; ++r)
                out[(size_t)(row + r) * EMB + col] = acc[i][j][r] + bv;
        }
    }
}

// ---------------------------------------------------------------------------
// Flash attention, transposed-score, static-max softmax.
// R14: 8 waves (512 thr); wave (qh = wave>>1, kh = wave&1) owns 32 q-rows
// (2 g-groups of 16) x 32 keys (kh-half of the 64-key tile).
//  - per wave per tile: 4 kf + 4 vf + 2 pf = 10 ds_read_b128 (R12: 18),
//    16 MFMA, 16 exp2 (unchanged). Per-CU LDS reads 288 -> 160.
//  - occupancy: 66KB LDS, 512 thr -> 2 blocks/CU, 16 waves/CU, 4 waves/SIMD
//    (same as R12; R13's regression was losing this).
//  - O/l partials (kh halves) combined once at end via f32 scratch aliased
//    over the ring buffers (after __syncthreads; ring data dead by then).
// Ring depth 3, one s_barrier/tile, counted s_waitcnt vmcnt(2).
// Grid: x = bh (32) -> XCD locality; y = q-tile (16).
// ---------------------------------------------------------------------------
__global__ __launch_bounds__(512) void attn(
        const unsigned short* __restrict__ Q,
        const unsigned short* __restrict__ K,
        const unsigned short* __restrict__ VT,
        unsigned short* __restrict__ O) {
    // one flat LDS block so the end-of-kernel f32 scratch can alias the ring
    __shared__ __align__(16) unsigned short smem[33792];   // 67584 B
    unsigned short (*sK )[64][64] = (unsigned short (*)[64][64])(smem);
    unsigned short (*sVT)[64][64] = (unsigned short (*)[64][64])(smem + 12288);
    unsigned short (*sP )[72]     = (unsigned short (*)[72])(smem + 24576);

    const int t    = threadIdx.x;
    const int wave = t >> 6, lane = t & 63;
    const int qh   = wave >> 1, kh = wave & 1;
    const int l15  = lane & 15, quad = lane >> 4;
    const int bh   = blockIdx.x;                 // XCD-locality key
    const int b    = bh >> 4, h = bh & 15;
    const int q0   = blockIdx.y * 128;
    const size_t rowbase = (size_t)b * SEQ;
    const int colbase  = h * HD;
    const size_t vtbase = (size_t)bh * HD * SEQ;
    const int srow = lane >> 3;
    const int sch  = ((lane & 7) ^ srow) * 8;

    // Q fragments in registers (pre-scaled by log2e/32 in GEMM epilogue);
    // this wave's 32 q-rows: q0 + qh*32 + g*16 + l15
    short8 qf[2][2];   // [g][ks]
    for (int g = 0; g < 2; ++g)
        for (int ks = 0; ks < 2; ++ks)
            qf[g][ks] = *(const short8*)
                &Q[(rowbase + q0 + qh * 32 + g * 16 + l15) * EMB
                   + colbase + ks * 32 + quad * 8];

    float l_part[2] = {0.f, 0.f};
    floatx4 o_acc[2][4] = {};   // [g][mi = d-frag]; col = q (l15)

    const int rr  = wave * 8;        // wave-uniform stage row base (8 waves x 8)
    const int row = rr + srow;       // this lane's stage row

    // prologue: stage tile 0 into buffer 0
    gl_lds16(&K[(rowbase + row) * EMB + colbase + sch], &sK[0][0][0] + rr * 64);
    gl_lds16(&VT[vtbase + (size_t)row * SEQ + sch],     &sVT[0][0][0] + rr * 64);

    int cur = 0;
    for (int it = 0; it < SEQ / 64; ++it) {
        if (it < SEQ / 64 - 1) {
            // stage tile it+1 into the ring slot last read at iter it-1
            int nb = cur + 1; if (nb == 3) nb = 0;
            int kt = (it + 1) * 64;
            gl_lds16(&K[(rowbase + kt + row) * EMB + colbase + sch],
                     &sK[nb][0][0] + rr * 64);
            gl_lds16(&VT[vtbase + (size_t)row * SEQ + kt + sch],
                     &sVT[nb][0][0] + rr * 64);
            asm volatile("s_waitcnt vmcnt(2)" ::: "memory");
        } else {
            asm volatile("s_waitcnt vmcnt(0)" ::: "memory");
        }
        asm volatile("s_barrier" ::: "memory");

        const unsigned short (*cK)[64]  = sK[cur];
        const unsigned short (*cVT)[64] = sVT[cur];

        // S^T = K Q^T over this wave's 32 keys:
        // s[g][m] rows = keys kh*32 + m*16 + quad*4 + r, col = q = l15
        floatx4 s[2][2] = {};
        for (int ks = 0; ks < 2; ++ks) {
            const int ch = (((ks * 4) + quad) ^ (l15 & 7)) * 8;
            short8 kf[2];
            for (int m = 0; m < 2; ++m)
                kf[m] = *(const short8*)&cK[kh * 32 + m * 16 + l15][ch];
            for (int g = 0; g < 2; ++g)
                for (int m = 0; m < 2; ++m)
                    s[g][m] = __builtin_amdgcn_mfma_f32_16x16x32_bf16(
                        kf[m], qf[g][ks], s[g][m], 0, 0, 0);
        }

        // p = exp2(s); per-lane l partial; pack to wave-private sP half-rows
        for (int g = 0; g < 2; ++g) {
            int prow = qh * 32 + g * 16 + l15;
            float lp = l_part[g];
            for (int m = 0; m < 2; ++m) {
                float p0 = __builtin_amdgcn_exp2f(s[g][m][0]);
                float p1 = __builtin_amdgcn_exp2f(s[g][m][1]);
                float p2 = __builtin_amdgcn_exp2f(s[g][m][2]);
                float p3 = __builtin_amdgcn_exp2f(s[g][m][3]);
                lp += (p0 + p1) + (p2 + p3);
                uint2 pk;
                pk.x = pk_bf16(p0, p1);
                pk.y = pk_bf16(p2, p3);
                *(uint2*)&sP[prow][kh * 32 + m * 16 + quad * 4] = pk;
            }
            l_part[g] = lp;
        }

        // O^T partial += V^T[:, kh-half] P^T[kh-half, :]
        // (sP half-rows are wave-private; no barrier needed)
        {
            const int ch = ((kh * 4 + quad) ^ (l15 & 7)) * 8;
            short8 vf[4];
            for (int mi = 0; mi < 4; ++mi)
                vf[mi] = *(const short8*)&cVT[mi * 16 + l15][ch];
            for (int g = 0; g < 2; ++g) {
                short8 pf = *(const short8*)
                    &sP[qh * 32 + g * 16 + l15][kh * 32 + quad * 8];
                for (int mi = 0; mi < 4; ++mi)
                    o_acc[g][mi] = __builtin_amdgcn_mfma_f32_16x16x32_bf16(
                        vf[mi], pf, o_acc[g][mi], 0, 0, 0);
            }
        }
        cur = cur + 1; if (cur == 3) cur = 0;
        // NO trailing barrier: next iter's single barrier protects the ring.
    }

    // reduce l across quads (this wave's 32 keys were spread over quad)
    float la[2];
    for (int g = 0; g < 2; ++g) {
        float v = l_part[g];
        v += __shfl_xor(v, 16, 64);
        v += __shfl_xor(v, 32, 64);
        la[g] = v;
    }

    // ---- combine kh halves via f32 scratch aliased over ring buffers ----
    __syncthreads();                      // all reads of sK/sVT done
    float* oscr = (float*)smem;           // [128][68] f32 = 34816 B
    float* lscr = (float*)smem + 128 * 68;// 128 f32 (ends at 35328 < 49152=sP)
    if (kh == 1) {
        for (int g = 0; g < 2; ++g) {
            int q = qh * 32 + g * 16 + l15;
            for (int mi = 0; mi < 4; ++mi)
                *(floatx4*)&oscr[q * 68 + mi * 16 + quad * 4] = o_acc[g][mi];
            if (quad == 0) lscr[q] = la[g];
        }
    }
    __syncthreads();
    if (kh == 0) {
        for (int g = 0; g < 2; ++g) {
            int q = qh * 32 + g * 16 + l15;
            const float inv_l = 1.0f / (la[g] + lscr[q]);
            for (int mi = 0; mi < 4; ++mi) {
                floatx4 o1 = *(const floatx4*)&oscr[q * 68 + mi * 16 + quad * 4];
                float c0 = (o_acc[g][mi][0] + o1[0]) * inv_l;
                float c1 = (o_acc[g][mi][1] + o1[1]) * inv_l;
                float c2 = (o_acc[g][mi][2] + o1[2]) * inv_l;
                float c3 = (o_acc[g][mi][3] + o1[3]) * inv_l;
                uint2 pk;
                pk.x = pk_bf16(c0, c1);
                pk.y = pk_bf16(c2, c3);
                *(uint2*)&sP[q][mi * 16 + quad * 4] = pk;
            }
        }
        __builtin_amdgcn_s_waitcnt(0);  // drain lgkm before wave-private re-read
        const int ql = lane >> 2, dh = (lane & 3) * 16;
        for (int g = 0; g < 2; ++g) {
            const size_t grow = rowbase + q0 + qh * 32 + g * 16 + ql;
            for (int i = 0; i < 2; ++i) {
                uint4 v = *(const uint4*)&sP[qh * 32 + g * 16 + ql][dh + i * 8];
                *(uint4*)&O[grow * EMB + colbase + dh + i * 8] = v;
            }
        }
    }
}

// ---------------------------------------------------------------------------
extern "C" void kernel_launch(void* const* d_in, const int* in_sizes, int n_in,
                              void* d_out, int out_size, void* d_ws, size_t ws_size,
                              hipStream_t stream) {
    const float* x  = (const float*)d_in[0];
    const float* Wq = (const float*)d_in[1];
    const float* bq = (const float*)d_in[2];
    const float* Wk = (const float*)d_in[3];
    const float* bk = (const float*)d_in[4];
    const float* Wv = (const float*)d_in[5];
    const float* bv = (const float*)d_in[6];
    const float* Wo = (const float*)d_in[7];
    const float* bo = (const float*)d_in[8];

    unsigned short* ws  = (unsigned short*)d_ws;
    unsigned short* xb  = ws;                // [4096][1024] bf16
    unsigned short* wqb = ws + 4194304;      // [1024][1024]
    unsigned short* wkb = ws + 5242880;
    unsigned short* wvb = ws + 6291456;
    unsigned short* wob = ws + 7340032;
    unsigned short* Qb  = ws + 8388608;      // [4096][1024] (pre-scaled)
    unsigned short* Kb  = ws + 12582912;     // [4096][1024]
    unsigned short* VTb = ws + 16777216;     // [32*64][2048] = V^T per (b,h)
    unsigned short* Ob  = ws + 20971520;     // attention output [4096][1024]

    convert_all<<<8192, 256, 0, stream>>>(x, Wq, Wk, Wv, Wo, ws);
    gemm_qkv<<<dim3(8, 32, 3), 256, 0, stream>>>(xb, wqb, wkb, wvb,
                                                 bq, bk, bv, Qb, Kb, VTb);
    attn<<<dim3(32, 16), 512, 0, stream>>>(Qb, Kb, VTb, Ob);
    gemm_out<<<dim3(16, 32), 256, 0, stream>>>(Ob, wob, bo, (float*)d_out);
}

// Round 4
// 174.299 us; speedup vs baseline: 1.0959x; 1.0322x over previous
//
#include <hip/hip_runtime.h>

// ---------------------------------------------------------------------------
// MultiHeadAttention: b=2, n=2048, EMB=1024, heads=16, head_dim=64
// R15: register-P attention via key relabeling.
//  R14 showed no pipe saturates (Mfma 27/VALU 44/LDS ~65%): the cost is
//  phase serialization under per-tile lockstep, with the P LDS round-trip
//  (ds_write -> lgkm wait -> ds_read) sitting serially between the softmax
//  VALU phase and PV. Fix: stage the K tile with ROWS PERMUTED (per 32-key
//  half: LDS row m*16+q*4+r holds global key q*8+m*4+r). Then each lane's
//  QK accumulators are exactly the 8 keys its PV B-fragment needs:
//  pf = 4 in-lane pk_bf16 words. Zero shuffles, zero LDS for P.
//  V^T stays linear; softmax l-sum is permutation-invariant.
//  + T5 s_setprio(1) around MFMA clusters.
//  - gemm_qkv / gemm_out / convert_all unchanged.
// ---------------------------------------------------------------------------

typedef short short8  __attribute__((ext_vector_type(8)));
typedef float floatx4 __attribute__((ext_vector_type(4)));

#define SEQ   2048
#define BATCH 2
#define NH    16
#define HD    64
#define EMB   1024

// softmax_e(E/32) == softmax_2(E * log2e/32); folded into Q.
#define QSCALE 0.045084220027780106f

__device__ __forceinline__ unsigned short f32_bf16(float f) {
    unsigned int u = __float_as_uint(f);
    u += 0x7FFF + ((u >> 16) & 1);      // round-to-nearest-even
    return (unsigned short)(u >> 16);
}

// pack two floats to bf16x2 (round-to-nearest, ties-away): 2 adds + 1 perm
__device__ __forceinline__ unsigned int pk_bf16(float lo, float hi) {
    return __builtin_amdgcn_perm(__float_as_uint(hi) + 0x8000u,
                                 __float_as_uint(lo) + 0x8000u, 0x07060302u);
}

// async global->LDS, 16B per lane; LDS dest = wave-uniform base + lane*16
__device__ __forceinline__ void gl_lds16(const unsigned short* g,
                                         unsigned short* l) {
    __builtin_amdgcn_global_load_lds(
        (const __attribute__((address_space(1))) unsigned int*)g,
        (__attribute__((address_space(3))) unsigned int*)l, 16, 0, 0);
}

// ---------------------------------------------------------------------------
// fp32 -> bf16 conversion for x, Wq, Wk, Wv, Wo (laid contiguously at ws+0)
// ---------------------------------------------------------------------------
__global__ __launch_bounds__(256) void convert_all(
        const float* __restrict__ x,  const float* __restrict__ wq,
        const float* __restrict__ wk, const float* __restrict__ wv,
        const float* __restrict__ wo, unsigned short* __restrict__ dst) {
    int i = (blockIdx.x * 256 + threadIdx.x) * 4;
    const float* src; int off;
    if      (i < 4194304) { src = x;  off = 0; }
    else if (i < 5242880) { src = wq; off = 4194304; }
    else if (i < 6291456) { src = wk; off = 5242880; }
    else if (i < 7340032) { src = wv; off = 6291456; }
    else                  { src = wo; off = 7340032; }
    float4 v = *(const float4*)(src + (i - off));
    uint2 o;
    o.x = pk_bf16(v.x, v.y);
    o.y = pk_bf16(v.z, v.w);
    *(uint2*)(dst + i) = o;
}

// ---------------------------------------------------------------------------
// QKV GEMM: C[4096,1024] = A[4096,1024] * B[1024,1024]^T + bias
// 256 thr / 4 waves, 128x128 tile, global_load_lds + XOR-chunk swizzle.
// MODE 0: bf16 | MODE 1: bf16*QSCALE (Q) | MODE 2: bf16 -> VT scatter (V)
// ---------------------------------------------------------------------------
template <int MODE>
__device__ __forceinline__ void gemm_bt_core(
        unsigned short (* __restrict__ sA)[64],
        unsigned short (* __restrict__ sB)[64],
        const unsigned short* __restrict__ A,
        const unsigned short* __restrict__ B,
        const float* __restrict__ bias,
        unsigned short* __restrict__ outb) {
    const int t    = threadIdx.x;
    const int wave = t >> 6, lane = t & 63;
    const int l15  = lane & 15, quad = lane >> 4;
    const int wm   = (wave >> 1) * 64, wn = (wave & 1) * 64;
    const int m0   = blockIdx.y * 128,  n0 = blockIdx.x * 128;
    const int srow = lane >> 3;                 // 0..7
    const int sch  = ((lane & 7) ^ srow) * 8;   // swizzled source chunk

    floatx4 acc[4][4] = {};

    for (int k0 = 0; k0 < EMB; k0 += 64) {
        for (int i = 0; i < 4; ++i) {
            int rr  = wave * 32 + i * 8;        // wave-uniform row base
            int row = rr + srow;
            gl_lds16(&A[(size_t)(m0 + row) * EMB + k0 + sch], &sA[0][0] + rr * 64);
            gl_lds16(&B[(size_t)(n0 + row) * EMB + k0 + sch], &sB[0][0] + rr * 64);
        }
        __syncthreads();
        for (int ks = 0; ks < 2; ++ks) {
            const int ch = (((ks * 4) + quad) ^ (l15 & 7)) * 8;
            short8 af[4], bf[4];
            for (int i = 0; i < 4; ++i)
                af[i] = *(const short8*)&sA[wm + i * 16 + l15][ch];
            for (int j = 0; j < 4; ++j)
                bf[j] = *(const short8*)&sB[wn + j * 16 + l15][ch];
            for (int i = 0; i < 4; ++i)
                for (int j = 0; j < 4; ++j)
                    acc[i][j] = __builtin_amdgcn_mfma_f32_16x16x32_bf16(
                        af[i], bf[j], acc[i][j], 0, 0, 0);
        }
        __syncthreads();
    }
    // C/D layout: col = lane&15, row = quad*4 + reg
    if (MODE == 2) {
        // V: write transposed VT[(b*16+h)*64 + d][seq]
        for (int i = 0; i < 4; ++i) {
            int row = m0 + wm + i * 16 + quad * 4;
            int bb  = row >> 11, seq = row & 2047;
            for (int j = 0; j < 4; ++j) {
                int col = n0 + wn + j * 16 + l15;
                float bv = bias[col];
                int vtrow = (bb * 16 + (col >> 6)) * 64 + (col & 63);
                uint2 pk;
                pk.x = pk_bf16(acc[i][j][0] + bv, acc[i][j][1] + bv);
                pk.y = pk_bf16(acc[i][j][2] + bv, acc[i][j][3] + bv);
                *(uint2*)&outb[(size_t)vtrow * SEQ + seq] = pk;
            }
        }
    } else {
        const float sc2 = (MODE == 1) ? QSCALE : 1.0f;
        for (int i = 0; i < 4; ++i) {
            int row = m0 + wm + i * 16 + quad * 4;
            for (int j = 0; j < 4; ++j) {
                int col = n0 + wn + j * 16 + l15;
                float bv = bias[col];
                for (int r = 0; r < 4; ++r) {
                    float v = (acc[i][j][r] + bv) * sc2;
                    outb[(size_t)(row + r) * EMB + col] = f32_bf16(v);
                }
            }
        }
    }
}

__global__ __launch_bounds__(256, 3) void gemm_qkv(
        const unsigned short* __restrict__ xb,
        const unsigned short* __restrict__ wq,
        const unsigned short* __restrict__ wk,
        const unsigned short* __restrict__ wv,
        const float* __restrict__ bq, const float* __restrict__ bk,
        const float* __restrict__ bv,
        unsigned short* __restrict__ Q, unsigned short* __restrict__ K,
        unsigned short* __restrict__ VT) {
    __shared__ unsigned short sA[128][64];
    __shared__ unsigned short sB[128][64];
    if      (blockIdx.z == 0) gemm_bt_core<1>(sA, sB, xb, wq, bq, Q);
    else if (blockIdx.z == 1) gemm_bt_core<0>(sA, sB, xb, wk, bk, K);
    else                      gemm_bt_core<2>(sA, sB, xb, wv, bv, VT);
}

// ---------------------------------------------------------------------------
// Output GEMM (fp32 out): 128x64 tile, 256 thr / 4 waves (wave = 32m x 64n),
// grid (16,32) = 512 blocks -> 2 blocks/CU, 8 waves/CU.
// ---------------------------------------------------------------------------
__global__ __launch_bounds__(256) void gemm_out(
        const unsigned short* __restrict__ A,
        const unsigned short* __restrict__ B,
        const float* __restrict__ bias, float* __restrict__ out) {
    __shared__ unsigned short sA[128][64];
    __shared__ unsigned short sB[64][64];
    const int t    = threadIdx.x;
    const int wave = t >> 6, lane = t & 63;
    const int l15  = lane & 15, quad = lane >> 4;
    const int wm   = wave * 32;
    const int m0   = blockIdx.y * 128,  n0 = blockIdx.x * 64;
    const int srow = lane >> 3;
    const int sch  = ((lane & 7) ^ srow) * 8;

    floatx4 acc[2][4] = {};

    for (int k0 = 0; k0 < EMB; k0 += 64) {
        {
            for (int i = 0; i < 4; ++i) {     // A: wave's 32 rows
                int rr = wave * 32 + i * 8;
                gl_lds16(&A[(size_t)(m0 + rr + srow) * EMB + k0 + sch],
                         &sA[0][0] + rr * 64);
            }
            for (int i = 0; i < 2; ++i) {     // B: wave's 16 rows
                int rr = wave * 16 + i * 8;
                gl_lds16(&B[(size_t)(n0 + rr + srow) * EMB + k0 + sch],
                         &sB[0][0] + rr * 64);
            }
        }
        __syncthreads();
        for (int ks = 0; ks < 2; ++ks) {
            const int ch = (((ks * 4) + quad) ^ (l15 & 7)) * 8;
            short8 af[2], bf[4];
            for (int i = 0; i < 2; ++i)
                af[i] = *(const short8*)&sA[wm + i * 16 + l15][ch];
            for (int j = 0; j < 4; ++j)
                bf[j] = *(const short8*)&sB[j * 16 + l15][ch];
            for (int i = 0; i < 2; ++i)
                for (int j = 0; j < 4; ++j)
                    acc[i][j] = __builtin_amdgcn_mfma_f32_16x16x32_bf16(
                        af[i], bf[j], acc[i][j], 0, 0, 0);
        }
        __syncthreads();
    }
    for (int i = 0; i < 2; ++i) {
        int row = m0 + wm + i * 16 + quad * 4;
        for (int j = 0; j < 4; ++j) {
            int col = n0 + j * 16 + l15;
            float bv = bias[col];
            for (int r = 0; r < 4; ++r)
                out[(size_t)(row + r) * EMB + col] = acc[i][j][r] + bv;
        }
    }
}

// ---------------------------------------------------------------------------
// Flash attention, transposed-score, static-max softmax.
// R15: 8 waves (512 thr); wave (qh = wave>>1, kh = wave&1) owns 32 q-rows
// (2 g-groups of 16) x 32 keys (kh-half of the 64-key tile).
//  - K STAGED ROW-PERMUTED: per 32-key half, LDS row (m*16+q*4+r) holds
//    global key (q*8+m*4+r). QK's accumulator (m, quad, r) then computes P
//    for exactly the key PV's B-fragment needs at word j = m*4+r:
//    pf = {pk(s[0r0],s[0r1]), pk(s[0r2],s[0r3]), pk(s[1r0],s[1r1]),
//          pk(s[1r2],s[1r3])} -- P never touches LDS during the loop.
//  - per wave per tile: 4 kf + 4 vf = 8 ds_read_b128 (R14: 10 + 4 writes),
//    16 MFMA, 16 exp2.
//  - vf reads issued BEFORE the softmax VALU phase (latency overlap).
//  - s_setprio(1) around both MFMA clusters (T5).
//  - O/l partials (kh halves) combined once at end via f32 scratch aliased
//    over the ring buffers.
// Ring depth 3, one s_barrier/tile, counted s_waitcnt vmcnt(2).
// Grid: x = bh (32) -> XCD locality; y = q-tile (16). 66KB LDS, 2 blk/CU.
// ---------------------------------------------------------------------------
__global__ __launch_bounds__(512) void attn(
        const unsigned short* __restrict__ Q,
        const unsigned short* __restrict__ K,
        const unsigned short* __restrict__ VT,
        unsigned short* __restrict__ O) {
    // one flat LDS block so the end-of-kernel f32 scratch can alias the ring
    __shared__ __align__(16) unsigned short smem[33792];   // 67584 B
    unsigned short (*sK )[64][64] = (unsigned short (*)[64][64])(smem);
    unsigned short (*sVT)[64][64] = (unsigned short (*)[64][64])(smem + 12288);
    unsigned short (*sP )[72]     = (unsigned short (*)[72])(smem + 24576);

    const int t    = threadIdx.x;
    const int wave = t >> 6, lane = t & 63;
    const int qh   = wave >> 1, kh = wave & 1;
    const int l15  = lane & 15, quad = lane >> 4;
    const int bh   = blockIdx.x;                 // XCD-locality key
    const int b    = bh >> 4, h = bh & 15;
    const int q0   = blockIdx.y * 128;
    const size_t rowbase = (size_t)b * SEQ;
    const int colbase  = h * HD;
    const size_t vtbase = (size_t)bh * HD * SEQ;
    const int srow = lane >> 3;
    const int sch  = ((lane & 7) ^ srow) * 8;

    // Q fragments in registers (pre-scaled by log2e/32 in GEMM epilogue);
    // this wave's 32 q-rows: q0 + qh*32 + g*16 + l15
    short8 qf[2][2];   // [g][ks]
    for (int g = 0; g < 2; ++g)
        for (int ks = 0; ks < 2; ++ks)
            qf[g][ks] = *(const short8*)
                &Q[(rowbase + q0 + qh * 32 + g * 16 + l15) * EMB
                   + colbase + ks * 32 + quad * 8];

    float l_part[2] = {0.f, 0.f};
    floatx4 o_acc[2][4] = {};   // [g][mi = d-frag]; col = q (l15)

    const int rr  = wave * 8;        // wave-uniform stage row base (8 waves x 8)
    const int row = rr + srow;       // this lane's LDS stage row
    // K row relabeling: LDS row (half*32 + m*16 + q*4 + r) <- global key
    // (half*32 + q*8 + m*4 + r). Source address is per-lane (legal).
    const int kw   = row & 31;
    const int krow = (row & 32) + ((kw >> 2) & 3) * 8 + ((kw >> 4) & 1) * 4
                     + (kw & 3);

    // prologue: stage tile 0 into buffer 0
    gl_lds16(&K[(rowbase + krow) * EMB + colbase + sch], &sK[0][0][0] + rr * 64);
    gl_lds16(&VT[vtbase + (size_t)row * SEQ + sch],      &sVT[0][0][0] + rr * 64);

    int cur = 0;
    for (int it = 0; it < SEQ / 64; ++it) {
        if (it < SEQ / 64 - 1) {
            // stage tile it+1 into the ring slot last read at iter it-1
            int nb = cur + 1; if (nb == 3) nb = 0;
            int kt = (it + 1) * 64;
            gl_lds16(&K[(rowbase + kt + krow) * EMB + colbase + sch],
                     &sK[nb][0][0] + rr * 64);
            gl_lds16(&VT[vtbase + (size_t)row * SEQ + kt + sch],
                     &sVT[nb][0][0] + rr * 64);
            asm volatile("s_waitcnt vmcnt(2)" ::: "memory");
        } else {
            asm volatile("s_waitcnt vmcnt(0)" ::: "memory");
        }
        asm volatile("s_barrier" ::: "memory");

        const unsigned short (*cK)[64]  = sK[cur];
        const unsigned short (*cVT)[64] = sVT[cur];

        // S^T = K Q^T over this wave's 32 keys (relabeled rows):
        // acc s[g][m] at (quad, r) = P^T[key quad*8 + m*4 + r][q]
        floatx4 s[2][2] = {};
        __builtin_amdgcn_s_setprio(1);
        for (int ks = 0; ks < 2; ++ks) {
            const int ch = (((ks * 4) + quad) ^ (l15 & 7)) * 8;
            short8 kf[2];
            for (int m = 0; m < 2; ++m)
                kf[m] = *(const short8*)&cK[kh * 32 + m * 16 + l15][ch];
            for (int g = 0; g < 2; ++g)
                for (int m = 0; m < 2; ++m)
                    s[g][m] = __builtin_amdgcn_mfma_f32_16x16x32_bf16(
                        kf[m], qf[g][ks], s[g][m], 0, 0, 0);
        }
        __builtin_amdgcn_s_setprio(0);

        // issue vf reads early: ds_read latency overlaps the softmax VALU
        short8 vf[4];
        {
            const int ch = ((kh * 4 + quad) ^ (l15 & 7)) * 8;
            for (int mi = 0; mi < 4; ++mi)
                vf[mi] = *(const short8*)&cVT[mi * 16 + l15][ch];
        }

        // p = exp2(s); l partial; pack pf IN REGISTER (key-relabeled):
        // pf word (m*2 + w) = pk(p[m][2w], p[m][2w+1]) -> B k-slot quad*8+j
        union { uint4 u; short8 s8; } pf[2];
        for (int g = 0; g < 2; ++g) {
            float lp = l_part[g];
            unsigned int w[4];
            for (int m = 0; m < 2; ++m) {
                float p0 = __builtin_amdgcn_exp2f(s[g][m][0]);
                float p1 = __builtin_amdgcn_exp2f(s[g][m][1]);
                float p2 = __builtin_amdgcn_exp2f(s[g][m][2]);
                float p3 = __builtin_amdgcn_exp2f(s[g][m][3]);
                lp += (p0 + p1) + (p2 + p3);
                w[m * 2 + 0] = pk_bf16(p0, p1);
                w[m * 2 + 1] = pk_bf16(p2, p3);
            }
            pf[g].u.x = w[0]; pf[g].u.y = w[1];
            pf[g].u.z = w[2]; pf[g].u.w = w[3];
            l_part[g] = lp;
        }

        // O^T partial += V^T[:, kh-half] P^T[kh-half, :]
        __builtin_amdgcn_s_setprio(1);
        for (int g = 0; g < 2; ++g)
            for (int mi = 0; mi < 4; ++mi)
                o_acc[g][mi] = __builtin_amdgcn_mfma_f32_16x16x32_bf16(
                    vf[mi], pf[g].s8, o_acc[g][mi], 0, 0, 0);
        __builtin_amdgcn_s_setprio(0);

        cur = cur + 1; if (cur == 3) cur = 0;
        // NO trailing barrier: next iter's single barrier protects the ring.
    }

    // reduce l across quads (this wave's 32 keys were spread over quad)
    float la[2];
    for (int g = 0; g < 2; ++g) {
        float v = l_part[g];
        v += __shfl_xor(v, 16, 64);
        v += __shfl_xor(v, 32, 64);
        la[g] = v;
    }

    // ---- combine kh halves via f32 scratch aliased over ring buffers ----
    __syncthreads();                      // all reads of sK/sVT done
    float* oscr = (float*)smem;           // [128][68] f32 = 34816 B
    float* lscr = (float*)smem + 128 * 68;// 128 f32 (ends at 35328 < 49152=sP)
    if (kh == 1) {
        for (int g = 0; g < 2; ++g) {
            int q = qh * 32 + g * 16 + l15;
            for (int mi = 0; mi < 4; ++mi)
                *(floatx4*)&oscr[q * 68 + mi * 16 + quad * 4] = o_acc[g][mi];
            if (quad == 0) lscr[q] = la[g];
        }
    }
    __syncthreads();
    if (kh == 0) {
        for (int g = 0; g < 2; ++g) {
            int q = qh * 32 + g * 16 + l15;
            const float inv_l = 1.0f / (la[g] + lscr[q]);
            for (int mi = 0; mi < 4; ++mi) {
                floatx4 o1 = *(const floatx4*)&oscr[q * 68 + mi * 16 + quad * 4];
                float c0 = (o_acc[g][mi][0] + o1[0]) * inv_l;
                float c1 = (o_acc[g][mi][1] + o1[1]) * inv_l;
                float c2 = (o_acc[g][mi][2] + o1[2]) * inv_l;
                float c3 = (o_acc[g][mi][3] + o1[3]) * inv_l;
                uint2 pk;
                pk.x = pk_bf16(c0, c1);
                pk.y = pk_bf16(c2, c3);
                *(uint2*)&sP[q][mi * 16 + quad * 4] = pk;
            }
        }
        __builtin_amdgcn_s_waitcnt(0);  // drain lgkm before wave-private re-read
        const int ql = lane >> 2, dh = (lane & 3) * 16;
        for (int g = 0; g < 2; ++g) {
            const size_t grow = rowbase + q0 + qh * 32 + g * 16 + ql;
            for (int i = 0; i < 2; ++i) {
                uint4 v = *(const uint4*)&sP[qh * 32 + g * 16 + ql][dh + i * 8];
                *(uint4*)&O[grow * EMB + colbase + dh + i * 8] = v;
            }
        }
    }
}

// ---------------------------------------------------------------------------
extern "C" void kernel_launch(void* const* d_in, const int* in_sizes, int n_in,
                              void* d_out, int out_size, void* d_ws, size_t ws_size,
                              hipStream_t stream) {
    const float* x  = (const float*)d_in[0];
    const float* Wq = (const float*)d_in[1];
    const float* bq = (const float*)d_in[2];
    const float* Wk = (const float*)d_in[3];
    const float* bk = (const float*)d_in[4];
    const float* Wv = (const float*)d_in[5];
    const float* bv = (const float*)d_in[6];
    const float* Wo = (const float*)d_in[7];
    const float* bo = (const float*)d_in[8];

    unsigned short* ws  = (unsigned short*)d_ws;
    unsigned short* xb  = ws;                // [4096][1024] bf16
    unsigned short* wqb = ws + 4194304;      // [1024][1024]
    unsigned short* wkb = ws + 5242880;
    unsigned short* wvb = ws + 6291456;
    unsigned short* wob = ws + 7340032;
    unsigned short* Qb  = ws + 8388608;      // [4096][1024] (pre-scaled)
    unsigned short* Kb  = ws + 12582912;     // [4096][1024]
    unsigned short* VTb = ws + 16777216;     // [32*64][2048] = V^T per (b,h)
    unsigned short* Ob  = ws + 20971520;     // attention output [4096][1024]

    convert_all<<<8192, 256, 0, stream>>>(x, Wq, Wk, Wv, Wo, ws);
    gemm_qkv<<<dim3(8, 32, 3), 256, 0, stream>>>(xb, wqb, wkb, wvb,
                                                 bq, bk, bv, Qb, Kb, VTb);
    attn<<<dim3(32, 16), 512, 0, stream>>>(Qb, Kb, VTb, Ob);
    gemm_out<<<dim3(16, 32), 256, 0, stream>>>(Ob, wob, bo, (float*)d_out);
}